// Round 7
// baseline (594.938 us; speedup 1.0000x reference)
//
#include <hip/hip_runtime.h>
#include <hip/hip_bf16.h>
#include <math.h>

// Problem constants (fixed by the reference setup)
#define NN   50000
#define DEG  16
#define IN_F 128
#define HID  64
#define NH   4
#define BB   64

#define NB   512     // persistent grid: 2 blocks/CU on 256 CUs

typedef unsigned short u16;
typedef unsigned int   u32;
typedef unsigned char  u8;

typedef __attribute__((ext_vector_type(8))) short  short8;  // 8 bf16 (4 VGPRs)
typedef __attribute__((ext_vector_type(4))) float  f32x4;   // MFMA accumulator
typedef __attribute__((ext_vector_type(2))) float  f32x2;

// bf16 helpers (RNE pack, cheap unpack via bit shift)
__device__ __forceinline__ u16 f2bf(float x) {
    u32 u = __float_as_uint(x);
    return (u16)((u + 0x7fffu + ((u >> 16) & 1u)) >> 16);
}
__device__ __forceinline__ float bf2f(u16 v) { return __uint_as_float(((u32)v) << 16); }

// fp8 e4m3 (OCP) helpers via HW converts
__device__ __forceinline__ u8 f2fp8(float x) {
    return (u8)(__builtin_amdgcn_cvt_pk_fp8_f32(x, x, 0, false) & 0xff);
}

// Software global barrier (device-scope; persistent-kernel pattern).
// Monotonic counter; target = NB * phase. Counter zeroed host-side per call.
__device__ __forceinline__ void gbar(u32* cnt, u32 target) {
    __syncthreads();
    if (threadIdx.x == 0) {
        __threadfence();   // release: prior global writes visible device-wide
        __hip_atomic_fetch_add(cnt, 1u, __ATOMIC_ACQ_REL, __HIP_MEMORY_SCOPE_AGENT);
        while (__hip_atomic_load(cnt, __ATOMIC_ACQUIRE, __HIP_MEMORY_SCOPE_AGENT) < target)
            __builtin_amdgcn_s_sleep(8);
    }
    __syncthreads();
    __threadfence();       // acquire side for all threads in the block
}

// ---------------------------------------------------------------------------
// Fused GAT pipeline: one persistent kernel, 5 phases, 4 global barriers.
// P1 k1_mfma -> P2 k2_attn_agg1 -> P3 k3_mfma -> P4 k4_attn_agg2 -> P5 k5.
// ---------------------------------------------------------------------------
__global__ __launch_bounds__(256, 2) void gat_fused(
    const int* __restrict__ feat_ids, const int* __restrict__ src,
    const int* __restrict__ user_ids, const int* __restrict__ item_ids,
    const float* __restrict__ emb,
    const float* __restrict__ W1, const float* __restrict__ a_l1,
    const float* __restrict__ a_r1, const float* __restrict__ b1,
    const float* __restrict__ W2, const float* __restrict__ a_l2,
    const float* __restrict__ a_r2, const float* __restrict__ b2,
    u32* __restrict__ gcnt,
    u8* __restrict__ f1q, u16* __restrict__ h1b,
    float* __restrict__ el1, float* __restrict__ er1,
    u8* __restrict__ f2q, float* __restrict__ el2, float* __restrict__ er2,
    float* __restrict__ h2,
    float* __restrict__ out_scores, float* __restrict__ out_labels,
    float* __restrict__ out_loss)
{
    const int bid  = blockIdx.x;
    const int tid  = threadIdx.x;
    const int wave = tid >> 6;
    const int lane = tid & 63;
    const int quad = lane >> 4;
    const int l16  = lane & 15;

    // ---- shared memory (per-phase; sums to ~18 KB, fine at 2 blocks/CU) ----
    __shared__ u16   sA1[16][136];     // P1: 16 x 128 bf16, pitch 136
    __shared__ u16   sA3[16][264];     // P3: 16 x 256 bf16, pitch 264
    __shared__ float spl[4][16], spr[4][16];   // P3 logit partials
    __shared__ int   ssrc[16][16];     // P2/P4
    __shared__ float salpha[16][17];   // P2/P4 (+1 pad)
    __shared__ float wsum[4];          // P5

    // ======================= P1: f1 = emb[ids] @ W1 ========================
    {
        const int colbase = wave * 64;   // wave == head
        short8 bfrag[4][4];
#pragma unroll
        for (int ct = 0; ct < 4; ++ct) {
            const int col = colbase + ct * 16 + l16;
#pragma unroll
            for (int ks = 0; ks < 4; ++ks) {
                const int k0 = ks * 32 + quad * 8;
                short8 b;
#pragma unroll
                for (int j = 0; j < 8; ++j)
                    b[j] = (short)f2bf(W1[(size_t)(k0 + j) * (NH * HID) + col]);
                bfrag[ct][ks] = b;
            }
        }
        float av_l[4], av_r[4];
#pragma unroll
        for (int ct = 0; ct < 4; ++ct) {
            av_l[ct] = a_l1[colbase + ct * 16 + l16];
            av_r[ct] = a_r1[colbase + ct * 16 + l16];
        }
        u8* myf1 = f1q + (size_t)wave * NN * HID;

        for (int rt = bid; rt < NN / 16; rt += NB) {
            const int n0 = rt * 16;
            __syncthreads();
            {
                const int r  = tid >> 4;
                const int c8 = (tid & 15) * 8;
                const float* srcp = emb + (size_t)feat_ids[n0 + r] * IN_F + c8;
                const float4 v0 = *(const float4*)(srcp);
                const float4 v1 = *(const float4*)(srcp + 4);
                u32* p = (u32*)&sA1[r][c8];
                p[0] = ((u32)f2bf(v0.y) << 16) | f2bf(v0.x);
                p[1] = ((u32)f2bf(v0.w) << 16) | f2bf(v0.z);
                p[2] = ((u32)f2bf(v1.y) << 16) | f2bf(v1.x);
                p[3] = ((u32)f2bf(v1.w) << 16) | f2bf(v1.z);
            }
            __syncthreads();

            f32x4 acc[4];
#pragma unroll
            for (int ct = 0; ct < 4; ++ct) acc[ct] = (f32x4){0.f, 0.f, 0.f, 0.f};
#pragma unroll
            for (int ks = 0; ks < 4; ++ks) {
                const short8 af = *(const short8*)&sA1[l16][ks * 32 + quad * 8];
#pragma unroll
                for (int ct = 0; ct < 4; ++ct)
                    acc[ct] = __builtin_amdgcn_mfma_f32_16x16x32_bf16(
                        af, bfrag[ct][ks], acc[ct], 0, 0, 0);
            }

            float pl[4] = {0.f, 0.f, 0.f, 0.f};
            float pr[4] = {0.f, 0.f, 0.f, 0.f};
#pragma unroll
            for (int ct = 0; ct < 4; ++ct) {
                const int colj = ct * 16 + l16;
#pragma unroll
                for (int reg = 0; reg < 4; ++reg) {
                    const int row = quad * 4 + reg;
                    const float v = acc[ct][reg];
                    myf1[(size_t)(n0 + row) * HID + colj] = f2fp8(v);
                    pl[reg] += v * av_l[ct];
                    pr[reg] += v * av_r[ct];
                }
            }
#pragma unroll
            for (int o = 8; o > 0; o >>= 1) {
#pragma unroll
                for (int reg = 0; reg < 4; ++reg) {
                    pl[reg] += __shfl_down(pl[reg], o);
                    pr[reg] += __shfl_down(pr[reg], o);
                }
            }
            if (l16 == 0) {
#pragma unroll
                for (int reg = 0; reg < 4; ++reg) {
                    const int n = n0 + quad * 4 + reg;
                    el1[(size_t)wave * NN + n] = pl[reg];
                    er1[(size_t)wave * NN + n] = pr[reg];
                }
            }
        }
    }
    gbar(gcnt, NB * 1);

    // ============ P2: layer-1 attention + aggregation (head epochs) =========
    {
        const int ns = tid >> 4;            // node-sub 0..15
        const int c4 = tid & 15;            // col-quad 0..15
        for (int u = bid; u < (NN / 16) * NH; u += NB) {
            const int h  = u / (NN / 16);   // h-major: epoch-ordered
            const int x  = u - h * (NN / 16);
            const int n0 = x * 16;
            __syncthreads();
            ssrc[ns][c4] = src[(n0 + ns) * DEG + c4];
            __syncthreads();
            {
                const int s = ssrc[ns][c4];
                float v = el1[(size_t)h * NN + s] + er1[(size_t)h * NN + (n0 + ns)];
                v = (v > 0.0f) ? v : 0.2f * v;
                salpha[ns][c4] = v;
            }
            __syncthreads();
            if (tid < 16) {
                float m = -INFINITY;
#pragma unroll
                for (int e = 0; e < DEG; ++e) m = fmaxf(m, salpha[tid][e]);
                float s = 0.0f;
#pragma unroll
                for (int e = 0; e < DEG; ++e) { float ex = expf(salpha[tid][e] - m); salpha[tid][e] = ex; s += ex; }
                const float inv = 1.0f / s;
#pragma unroll
                for (int e = 0; e < DEG; ++e) salpha[tid][e] *= inv;
            }
            __syncthreads();

            const u8* tab = f1q + (size_t)h * NN * HID;
            float a0 = 0.f, a1 = 0.f, a2 = 0.f, a3 = 0.f;
#pragma unroll
            for (int e = 0; e < DEG; ++e) {
                const u32 uu = *(const u32*)(tab + (size_t)ssrc[ns][e] * HID + 4 * c4);
                const float al = salpha[ns][e];
                const f32x2 lo = __builtin_amdgcn_cvt_pk_f32_fp8(uu, false);
                const f32x2 hi = __builtin_amdgcn_cvt_pk_f32_fp8(uu, true);
                a0 += al * lo.x; a1 += al * lo.y;
                a2 += al * hi.x; a3 += al * hi.y;
            }
            const float4 bv = *(const float4*)(b1 + h * HID + 4 * c4);
            ushort4 o;
            o.x = f2bf(fmaxf(a0 + bv.x, 0.0f));
            o.y = f2bf(fmaxf(a1 + bv.y, 0.0f));
            o.z = f2bf(fmaxf(a2 + bv.z, 0.0f));
            o.w = f2bf(fmaxf(a3 + bv.w, 0.0f));
            *(ushort4*)(h1b + (size_t)(n0 + ns) * (NH * HID) + h * HID + 4 * c4) = o;
        }
    }
    gbar(gcnt, NB * 2);

    // ======================= P3: f2 = h1 @ W2 (MFMA) ========================
    {
        const int col = wave * 16 + l16;
        short8 bfrag[8];
#pragma unroll
        for (int ks = 0; ks < 8; ++ks) {
            const int k0 = ks * 32 + quad * 8;
            short8 b;
#pragma unroll
            for (int j = 0; j < 8; ++j)
                b[j] = (short)f2bf(W2[(size_t)(k0 + j) * HID + col]);
            bfrag[ks] = b;
        }
        const float avl = a_l2[col];
        const float avr = a_r2[col];

        for (int rt = bid; rt < NN / 16; rt += NB) {
            const int n0 = rt * 16;
            __syncthreads();
            {
                const int r  = tid >> 4;
                const int c0 = (tid & 15) * 16;
                const uint4 v0 = *(const uint4*)(h1b + (size_t)(n0 + r) * (NH * HID) + c0);
                const uint4 v1 = *(const uint4*)(h1b + (size_t)(n0 + r) * (NH * HID) + c0 + 8);
                *(uint4*)&sA3[r][c0]     = v0;
                *(uint4*)&sA3[r][c0 + 8] = v1;
            }
            __syncthreads();

            f32x4 acc = (f32x4){0.f, 0.f, 0.f, 0.f};
#pragma unroll
            for (int ks = 0; ks < 8; ++ks) {
                const short8 af = *(const short8*)&sA3[l16][ks * 32 + quad * 8];
                acc = __builtin_amdgcn_mfma_f32_16x16x32_bf16(af, bfrag[ks], acc, 0, 0, 0);
            }

            float pl[4], pr[4];
#pragma unroll
            for (int reg = 0; reg < 4; ++reg) {
                const int row = quad * 4 + reg;
                const float v = acc[reg];
                f2q[(size_t)(n0 + row) * HID + col] = f2fp8(v);
                pl[reg] = v * avl;
                pr[reg] = v * avr;
            }
#pragma unroll
            for (int o = 8; o > 0; o >>= 1) {
#pragma unroll
                for (int reg = 0; reg < 4; ++reg) {
                    pl[reg] += __shfl_down(pl[reg], o);
                    pr[reg] += __shfl_down(pr[reg], o);
                }
            }
            if (l16 == 0) {
#pragma unroll
                for (int reg = 0; reg < 4; ++reg) {
                    spl[wave][quad * 4 + reg] = pl[reg];
                    spr[wave][quad * 4 + reg] = pr[reg];
                }
            }
            __syncthreads();
            if (tid < 16) {
                el2[n0 + tid] = spl[0][tid] + spl[1][tid] + spl[2][tid] + spl[3][tid];
                er2[n0 + tid] = spr[0][tid] + spr[1][tid] + spr[2][tid] + spr[3][tid];
            }
        }
    }
    gbar(gcnt, NB * 3);

    // ================ P4: layer-2 attention + aggregation ===================
    {
        const int ns = tid >> 4;
        const int c4 = tid & 15;
        for (int x = bid; x < NN / 16; x += NB) {
            const int n0 = x * 16;
            __syncthreads();
            ssrc[ns][c4] = src[(n0 + ns) * DEG + c4];
            __syncthreads();
            {
                const int s = ssrc[ns][c4];
                float v = el2[s] + er2[n0 + ns];
                v = (v > 0.0f) ? v : 0.2f * v;
                salpha[ns][c4] = v;
            }
            __syncthreads();
            if (tid < 16) {
                float m = -INFINITY;
#pragma unroll
                for (int e = 0; e < DEG; ++e) m = fmaxf(m, salpha[tid][e]);
                float s = 0.0f;
#pragma unroll
                for (int e = 0; e < DEG; ++e) { float ex = expf(salpha[tid][e] - m); salpha[tid][e] = ex; s += ex; }
                const float inv = 1.0f / s;
#pragma unroll
                for (int e = 0; e < DEG; ++e) salpha[tid][e] *= inv;
            }
            __syncthreads();

            float a0 = 0.f, a1 = 0.f, a2 = 0.f, a3 = 0.f;
#pragma unroll
            for (int e = 0; e < DEG; ++e) {
                const u32 uu = *(const u32*)(f2q + (size_t)ssrc[ns][e] * HID + 4 * c4);
                const float al = salpha[ns][e];
                const f32x2 lo = __builtin_amdgcn_cvt_pk_f32_fp8(uu, false);
                const f32x2 hi = __builtin_amdgcn_cvt_pk_f32_fp8(uu, true);
                a0 += al * lo.x; a1 += al * lo.y;
                a2 += al * hi.x; a3 += al * hi.y;
            }
            const float4 bv = *(const float4*)(b2 + 4 * c4);
            float4 o = make_float4(a0 + bv.x, a1 + bv.y, a2 + bv.z, a3 + bv.w);
            *(float4*)(h2 + (size_t)(n0 + ns) * HID + 4 * c4) = o;
        }
    }
    gbar(gcnt, NB * 4);

    // ==================== P5: scores / labels / CE loss =====================
    if (bid == 0) {
        const int w = wave;
        const int j = lane;
        float lsum = 0.0f;
#pragma unroll
        for (int r = 0; r < 16; ++r) {
            const int i = r * 4 + w;
            const float s = h2[(size_t)user_ids[i] * HID + j] * h2[(size_t)item_ids[i] * HID + j];
            out_scores[i * BB + j] = s;
            out_labels[i * BB + j] = (i == j) ? 1.0f : 0.0f;

            float m = s;
#pragma unroll
            for (int o = 32; o > 0; o >>= 1) m = fmaxf(m, __shfl_down(m, o));
            m = __shfl(m, 0);
            float ex = expf(s - m);
#pragma unroll
            for (int o = 32; o > 0; o >>= 1) ex += __shfl_down(ex, o);
            const float sii = __shfl(s, i);
            if (j == 0) lsum += -(sii - m - logf(ex));
        }
        if (j == 0) wsum[w] = lsum;
        __syncthreads();
        if (tid == 0)
            out_loss[0] = (wsum[0] + wsum[1] + wsum[2] + wsum[3]) * (1.0f / (float)BB);
    }
}

// ---------------------------------------------------------------------------
extern "C" void kernel_launch(void* const* d_in, const int* in_sizes, int n_in,
                              void* d_out, int out_size, void* d_ws, size_t ws_size,
                              hipStream_t stream)
{
    const int*   feat_ids = (const int*)  d_in[0];
    const int*   src      = (const int*)  d_in[1];
    // d_in[2] = dst — structurally repeat(arange(N),16); not needed at runtime
    const int*   user_ids = (const int*)  d_in[3];
    const int*   item_ids = (const int*)  d_in[4];
    const float* emb      = (const float*)d_in[5];
    const float* W1       = (const float*)d_in[6];
    const float* a_l1     = (const float*)d_in[7];
    const float* a_r1     = (const float*)d_in[8];
    const float* b1       = (const float*)d_in[9];
    const float* W2       = (const float*)d_in[10];
    const float* a_l2     = (const float*)d_in[11];
    const float* a_r2     = (const float*)d_in[12];
    const float* b2       = (const float*)d_in[13];

    float* out = (float*)d_out;
    float* out_loss   = out;            // [1]
    float* out_scores = out + 1;        // [B*B]
    float* out_labels = out + 1 + BB * BB;

    // Workspace carve. Slot 0: global-barrier counter (zeroed every call).
    u32*   gcnt = (u32*)d_ws;
    u8*    base = (u8*)d_ws + 256;
    u8*    f1q  = base;                                    // [4][N][64] fp8
    u16*   h1b  = (u16*)(f1q + (size_t)NH * NN * HID);     // N*256 bf16
    float* el1  = (float*)(h1b + (size_t)NN * (NH * HID)); // [4][N]
    float* er1  = el1 + (size_t)NH * NN;                   // [4][N]
    u8*    f2q  = (u8*)(er1 + (size_t)NH * NN);            // N*64 fp8
    float* el2  = (float*)(f2q + (size_t)NN * HID);        // N
    float* er2  = el2 + NN;                                // N
    float* h2   = er2 + NN;                                // N*64 fp32

    hipMemsetAsync(gcnt, 0, sizeof(u32), stream);          // capture-safe
    gat_fused<<<NB, 256, 0, stream>>>(
        feat_ids, src, user_ids, item_ids, emb,
        W1, a_l1, a_r1, b1, W2, a_l2, a_r2, b2,
        gcnt, f1q, h1b, el1, er1, f2q, el2, er2, h2,
        out_scores, out_labels, out_loss);
}

// Round 8
// 177.848 us; speedup vs baseline: 3.3452x; 3.3452x over previous
//
#include <hip/hip_runtime.h>
#include <hip/hip_bf16.h>
#include <math.h>

// Problem constants (fixed by the reference setup)
#define NN   50000
#define DEG  16
#define IN_F 128
#define HID  64
#define NH   4
#define BB   64

typedef unsigned short u16;
typedef unsigned int   u32;
typedef unsigned char  u8;

typedef __attribute__((ext_vector_type(8))) short  short8;  // 8 bf16 (4 VGPRs)
typedef __attribute__((ext_vector_type(4))) float  f32x4;   // MFMA accumulator
typedef __attribute__((ext_vector_type(2))) float  f32x2;

// bf16 helpers (RNE pack, cheap unpack via bit shift)
__device__ __forceinline__ u16 f2bf(float x) {
    u32 u = __float_as_uint(x);
    return (u16)((u + 0x7fffu + ((u >> 16) & 1u)) >> 16);
}
__device__ __forceinline__ float bf2f(u16 v) { return __uint_as_float(((u32)v) << 16); }

// fp8 e4m3 (OCP) helpers via HW converts
__device__ __forceinline__ u8 f2fp8(float x) {
    return (u8)(__builtin_amdgcn_cvt_pk_fp8_f32(x, x, 0, false) & 0xff);
}

// ---------------------------------------------------------------------------
// k1: f1 = emb[feat_ids] @ W1 via MFMA 16x16x32 bf16.
// f1 stored fp8 e4m3, HEAD-SLICED: f1q[h][n][64] (4 tables x 3.2 MB, each
// fits a 4 MiB per-XCD L2 -> k2's gather is L2-resident per head epoch).
// el1/er1 stored [h][n] (fp32, from fp32 accumulators).
// ---------------------------------------------------------------------------
#define K1_GRID 512
__global__ __launch_bounds__(256) void k1_mfma(
    const int* __restrict__ feat_ids, const float* __restrict__ emb,
    const float* __restrict__ W1, const float* __restrict__ a_l1,
    const float* __restrict__ a_r1,
    u8* __restrict__ f1q, float* __restrict__ el1, float* __restrict__ er1)
{
    const int tid  = threadIdx.x;
    const int wave = tid >> 6;          // 0..3 == head
    const int lane = tid & 63;
    const int quad = lane >> 4;         // 0..3
    const int l16  = lane & 15;
    const int colbase = wave * 64;

    // B fragments: lane element j holds W1[ks*32+quad*8+j][colbase+ct*16+l16]
    short8 bfrag[4][4];
#pragma unroll
    for (int ct = 0; ct < 4; ++ct) {
        const int col = colbase + ct * 16 + l16;
#pragma unroll
        for (int ks = 0; ks < 4; ++ks) {
            const int k0 = ks * 32 + quad * 8;
            short8 b;
#pragma unroll
            for (int j = 0; j < 8; ++j)
                b[j] = (short)f2bf(W1[(size_t)(k0 + j) * (NH * HID) + col]);
            bfrag[ct][ks] = b;
        }
    }

    float av_l[4], av_r[4];
#pragma unroll
    for (int ct = 0; ct < 4; ++ct) {
        av_l[ct] = a_l1[colbase + ct * 16 + l16];
        av_r[ct] = a_r1[colbase + ct * 16 + l16];
    }

    u8* myf1 = f1q + (size_t)wave * NN * HID;   // this head's table

    __shared__ u16 sA[16][136];   // 16 rows x 128 k bf16, pitch 136

    for (int rt = blockIdx.x; rt < NN / 16; rt += K1_GRID) {
        const int n0 = rt * 16;
        __syncthreads();
        {
            const int r  = tid >> 4;
            const int c8 = (tid & 15) * 8;
            const float* srcp = emb + (size_t)feat_ids[n0 + r] * IN_F + c8;
            const float4 v0 = *(const float4*)(srcp);
            const float4 v1 = *(const float4*)(srcp + 4);
            u32* p = (u32*)&sA[r][c8];
            p[0] = ((u32)f2bf(v0.y) << 16) | f2bf(v0.x);
            p[1] = ((u32)f2bf(v0.w) << 16) | f2bf(v0.z);
            p[2] = ((u32)f2bf(v1.y) << 16) | f2bf(v1.x);
            p[3] = ((u32)f2bf(v1.w) << 16) | f2bf(v1.z);
        }
        __syncthreads();

        f32x4 acc[4];
#pragma unroll
        for (int ct = 0; ct < 4; ++ct) acc[ct] = (f32x4){0.f, 0.f, 0.f, 0.f};

#pragma unroll
        for (int ks = 0; ks < 4; ++ks) {
            const short8 af = *(const short8*)&sA[l16][ks * 32 + quad * 8];
#pragma unroll
            for (int ct = 0; ct < 4; ++ct)
                acc[ct] = __builtin_amdgcn_mfma_f32_16x16x32_bf16(
                    af, bfrag[ct][ks], acc[ct], 0, 0, 0);
        }

        // epilogue: fp8 store (head-sliced) + fused logits (fp32)
        float pl[4] = {0.f, 0.f, 0.f, 0.f};
        float pr[4] = {0.f, 0.f, 0.f, 0.f};
#pragma unroll
        for (int ct = 0; ct < 4; ++ct) {
            const int colj = ct * 16 + l16;           // 0..63 within head
#pragma unroll
            for (int reg = 0; reg < 4; ++reg) {
                const int row = quad * 4 + reg;
                const float v = acc[ct][reg];
                myf1[(size_t)(n0 + row) * HID + colj] = f2fp8(v);
                pl[reg] += v * av_l[ct];
                pr[reg] += v * av_r[ct];
            }
        }
#pragma unroll
        for (int o = 8; o > 0; o >>= 1) {
#pragma unroll
            for (int reg = 0; reg < 4; ++reg) {
                pl[reg] += __shfl_down(pl[reg], o);
                pr[reg] += __shfl_down(pr[reg], o);
            }
        }
        if (l16 == 0) {
#pragma unroll
            for (int reg = 0; reg < 4; ++reg) {
                const int n = n0 + quad * 4 + reg;
                el1[(size_t)wave * NN + n] = pl[reg];
                er1[(size_t)wave * NN + n] = pr[reg];
            }
        }
    }
}

// ---------------------------------------------------------------------------
// k2: layer-1 attention softmax + aggregation, HEAD-EPOCH version.
// grid (3125, NH); blockIdx.y = head (x-fastest dispatch -> all XCDs work one
// 3.2 MB head slice at a time -> L2-resident gather).
// Block: 16 nodes x 16 col-quads. fp8 gather, fp32 acc, fp8 h1 out.
// ---------------------------------------------------------------------------
__global__ __launch_bounds__(256) void k2_attn_agg1(
    const int* __restrict__ src, const u8* __restrict__ f1q,
    const float* __restrict__ el1, const float* __restrict__ er1,
    const float* __restrict__ b1, u8* __restrict__ h1q)
{
    const int h   = blockIdx.y;
    const int n0  = blockIdx.x * 16;
    const int tid = threadIdx.x;
    const int ns  = tid >> 4;               // node-sub 0..15
    const int c4  = tid & 15;               // col-quad 0..15 (cols 4c4..4c4+3)

    __shared__ int   ssrc[16][16];
    __shared__ float salpha[16][17];        // +1 pad

    ssrc[ns][c4] = src[(n0 + ns) * DEG + c4];
    __syncthreads();

    {   // logits: thread (ns, e=c4)
        const int s = ssrc[ns][c4];
        float v = el1[(size_t)h * NN + s] + er1[(size_t)h * NN + (n0 + ns)];
        v = (v > 0.0f) ? v : 0.2f * v;
        salpha[ns][c4] = v;
    }
    __syncthreads();

    if (tid < 16) {                         // per-node 16-way softmax
        float m = -INFINITY;
#pragma unroll
        for (int e = 0; e < DEG; ++e) m = fmaxf(m, salpha[tid][e]);
        float s = 0.0f;
#pragma unroll
        for (int e = 0; e < DEG; ++e) { float ex = expf(salpha[tid][e] - m); salpha[tid][e] = ex; s += ex; }
        const float inv = 1.0f / s;
#pragma unroll
        for (int e = 0; e < DEG; ++e) salpha[tid][e] *= inv;
    }
    __syncthreads();

    const u8* tab = f1q + (size_t)h * NN * HID;
    float a0 = 0.f, a1 = 0.f, a2 = 0.f, a3 = 0.f;
#pragma unroll
    for (int e = 0; e < DEG; ++e) {
        const u32 u = *(const u32*)(tab + (size_t)ssrc[ns][e] * HID + 4 * c4);
        const float al = salpha[ns][e];
        const f32x2 lo = __builtin_amdgcn_cvt_pk_f32_fp8(u, false);
        const f32x2 hi = __builtin_amdgcn_cvt_pk_f32_fp8(u, true);
        a0 += al * lo.x; a1 += al * lo.y;
        a2 += al * hi.x; a3 += al * hi.y;
    }
    const float4 bv = *(const float4*)(b1 + h * HID + 4 * c4);
    // relu + fp8 pack (4 elems -> one u32)
    u32 o = __builtin_amdgcn_cvt_pk_fp8_f32(fmaxf(a0 + bv.x, 0.0f),
                                            fmaxf(a1 + bv.y, 0.0f), 0, false);
    o = __builtin_amdgcn_cvt_pk_fp8_f32(fmaxf(a2 + bv.z, 0.0f),
                                        fmaxf(a3 + bv.w, 0.0f), o, true);
    *(u32*)(h1q + (size_t)(n0 + ns) * (NH * HID) + h * HID + 4 * c4) = o;
}

// ---------------------------------------------------------------------------
// k3: f2 = h1 @ W2 via MFMA 16x16x32 bf16, K=256. A staged fp8 -> bf16 LDS.
// f2 stored fp8 (3.2 MB -> k4 gather L2-resident). el2/er2 fused (fp32 acc).
// ---------------------------------------------------------------------------
#define K3_GRID 512
__global__ __launch_bounds__(256) void k3_mfma(
    const u8* __restrict__ h1q, const float* __restrict__ W2,
    const float* __restrict__ a_l2, const float* __restrict__ a_r2,
    u8* __restrict__ f2q, float* __restrict__ el2, float* __restrict__ er2)
{
    const int tid  = threadIdx.x;
    const int wave = tid >> 6;
    const int lane = tid & 63;
    const int quad = lane >> 4;
    const int l16  = lane & 15;
    const int col  = wave * 16 + l16;

    short8 bfrag[8];
#pragma unroll
    for (int ks = 0; ks < 8; ++ks) {
        const int k0 = ks * 32 + quad * 8;
        short8 b;
#pragma unroll
        for (int j = 0; j < 8; ++j)
            b[j] = (short)f2bf(W2[(size_t)(k0 + j) * HID + col]);
        bfrag[ks] = b;
    }
    const float avl = a_l2[col];
    const float avr = a_r2[col];

    __shared__ u16   sA[16][264];       // 16 rows x 256 k bf16, pitch 264
    __shared__ float spl[4][16];
    __shared__ float spr[4][16];

    for (int rt = blockIdx.x; rt < NN / 16; rt += K3_GRID) {
        const int n0 = rt * 16;
        __syncthreads();
        {   // stage A: 16 fp8 elems/thread -> bf16 LDS
            const int r  = tid >> 4;
            const int c0 = (tid & 15) * 16;
            const uint4 v = *(const uint4*)(h1q + (size_t)(n0 + r) * (NH * HID) + c0);
            u32* dst = (u32*)&sA[r][c0];
            const u32 ww[4] = {v.x, v.y, v.z, v.w};
#pragma unroll
            for (int i = 0; i < 4; ++i) {
                const f32x2 lo = __builtin_amdgcn_cvt_pk_f32_fp8(ww[i], false);
                const f32x2 hi = __builtin_amdgcn_cvt_pk_f32_fp8(ww[i], true);
                dst[2 * i]     = ((u32)f2bf(lo.y) << 16) | f2bf(lo.x);
                dst[2 * i + 1] = ((u32)f2bf(hi.y) << 16) | f2bf(hi.x);
            }
        }
        __syncthreads();

        f32x4 acc = (f32x4){0.f, 0.f, 0.f, 0.f};
#pragma unroll
        for (int ks = 0; ks < 8; ++ks) {
            const short8 af = *(const short8*)&sA[l16][ks * 32 + quad * 8];
            acc = __builtin_amdgcn_mfma_f32_16x16x32_bf16(af, bfrag[ks], acc, 0, 0, 0);
        }

        float pl[4], pr[4];
#pragma unroll
        for (int reg = 0; reg < 4; ++reg) {
            const int row = quad * 4 + reg;
            const float v = acc[reg];
            f2q[(size_t)(n0 + row) * HID + col] = f2fp8(v);
            pl[reg] = v * avl;
            pr[reg] = v * avr;
        }
#pragma unroll
        for (int o = 8; o > 0; o >>= 1) {
#pragma unroll
            for (int reg = 0; reg < 4; ++reg) {
                pl[reg] += __shfl_down(pl[reg], o);
                pr[reg] += __shfl_down(pr[reg], o);
            }
        }
        if (l16 == 0) {
#pragma unroll
            for (int reg = 0; reg < 4; ++reg) {
                spl[wave][quad * 4 + reg] = pl[reg];
                spr[wave][quad * 4 + reg] = pr[reg];
            }
        }
        __syncthreads();
        if (tid < 16) {
            el2[n0 + tid] = spl[0][tid] + spl[1][tid] + spl[2][tid] + spl[3][tid];
            er2[n0 + tid] = spr[0][tid] + spr[1][tid] + spr[2][tid] + spr[3][tid];
        }
    }
}

// ---------------------------------------------------------------------------
// k4: layer-2 attention (H=1) + aggregation -> h2 (N x 64 fp32).
// fp8 gather from 3.2 MB L2-resident table.
// ---------------------------------------------------------------------------
__global__ __launch_bounds__(256) void k4_attn_agg2(
    const int* __restrict__ src, const u8* __restrict__ f2q,
    const float* __restrict__ el2, const float* __restrict__ er2,
    const float* __restrict__ b2, float* __restrict__ h2)
{
    const int n0  = blockIdx.x * 16;
    const int tid = threadIdx.x;
    const int ns  = tid >> 4;
    const int c4  = tid & 15;

    __shared__ int   ssrc[16][16];
    __shared__ float salpha[16][17];

    ssrc[ns][c4] = src[(n0 + ns) * DEG + c4];
    __syncthreads();

    {
        const int s = ssrc[ns][c4];
        float v = el2[s] + er2[n0 + ns];
        v = (v > 0.0f) ? v : 0.2f * v;
        salpha[ns][c4] = v;
    }
    __syncthreads();

    if (tid < 16) {
        float m = -INFINITY;
#pragma unroll
        for (int e = 0; e < DEG; ++e) m = fmaxf(m, salpha[tid][e]);
        float s = 0.0f;
#pragma unroll
        for (int e = 0; e < DEG; ++e) { float ex = expf(salpha[tid][e] - m); salpha[tid][e] = ex; s += ex; }
        const float inv = 1.0f / s;
#pragma unroll
        for (int e = 0; e < DEG; ++e) salpha[tid][e] *= inv;
    }
    __syncthreads();

    float a0 = 0.f, a1 = 0.f, a2 = 0.f, a3 = 0.f;
#pragma unroll
    for (int e = 0; e < DEG; ++e) {
        const u32 u = *(const u32*)(f2q + (size_t)ssrc[ns][e] * HID + 4 * c4);
        const float al = salpha[ns][e];
        const f32x2 lo = __builtin_amdgcn_cvt_pk_f32_fp8(u, false);
        const f32x2 hi = __builtin_amdgcn_cvt_pk_f32_fp8(u, true);
        a0 += al * lo.x; a1 += al * lo.y;
        a2 += al * hi.x; a3 += al * hi.y;
    }
    const float4 bv = *(const float4*)(b2 + 4 * c4);
    float4 o = make_float4(a0 + bv.x, a1 + bv.y, a2 + bv.z, a3 + bv.w);
    *(float4*)(h2 + (size_t)(n0 + ns) * HID + 4 * c4) = o;
}

// ---------------------------------------------------------------------------
// k5: scores, labels, CE loss — single block, 4 waves x 16 rows each.
// ---------------------------------------------------------------------------
__global__ __launch_bounds__(256) void k5_score_loss(
    const float* __restrict__ h2, const int* __restrict__ user_ids,
    const int* __restrict__ item_ids,
    float* __restrict__ out_scores, float* __restrict__ out_labels,
    float* __restrict__ out_loss)
{
    const int w = threadIdx.x >> 6;         // 0..3
    const int j = threadIdx.x & 63;
    __shared__ float wsum[4];
    float lsum = 0.0f;

#pragma unroll
    for (int r = 0; r < 16; ++r) {
        const int i = r * 4 + w;            // row 0..63
        const float s = h2[(size_t)user_ids[i] * HID + j] * h2[(size_t)item_ids[i] * HID + j];
        out_scores[i * BB + j] = s;
        out_labels[i * BB + j] = (i == j) ? 1.0f : 0.0f;

        float m = s;
#pragma unroll
        for (int o = 32; o > 0; o >>= 1) m = fmaxf(m, __shfl_down(m, o));
        m = __shfl(m, 0);
        float ex = expf(s - m);
#pragma unroll
        for (int o = 32; o > 0; o >>= 1) ex += __shfl_down(ex, o);
        const float sii = __shfl(s, i);
        if (j == 0) lsum += -(sii - m - logf(ex));
    }
    if (j == 0) wsum[w] = lsum;
    __syncthreads();
    if (threadIdx.x == 0)
        out_loss[0] = (wsum[0] + wsum[1] + wsum[2] + wsum[3]) * (1.0f / (float)BB);
}

// ---------------------------------------------------------------------------
extern "C" void kernel_launch(void* const* d_in, const int* in_sizes, int n_in,
                              void* d_out, int out_size, void* d_ws, size_t ws_size,
                              hipStream_t stream)
{
    const int*   feat_ids = (const int*)  d_in[0];
    const int*   src      = (const int*)  d_in[1];
    // d_in[2] = dst — structurally repeat(arange(N),16); not needed at runtime
    const int*   user_ids = (const int*)  d_in[3];
    const int*   item_ids = (const int*)  d_in[4];
    const float* emb      = (const float*)d_in[5];
    const float* W1       = (const float*)d_in[6];
    const float* a_l1     = (const float*)d_in[7];
    const float* a_r1     = (const float*)d_in[8];
    const float* b1       = (const float*)d_in[9];
    const float* W2       = (const float*)d_in[10];
    const float* a_l2     = (const float*)d_in[11];
    const float* a_r2     = (const float*)d_in[12];
    const float* b2       = (const float*)d_in[13];

    float* out = (float*)d_out;
    float* out_loss   = out;            // [1]
    float* out_scores = out + 1;        // [B*B]
    float* out_labels = out + 1 + BB * BB;

    // Workspace carve (~45 MB)
    u8*    f1q = (u8*)d_ws;                               // [4][N][64] fp8
    u8*    h1q = f1q + (size_t)NH * NN * HID;             // N*256 fp8
    float* el1 = (float*)(h1q + (size_t)NN * (NH * HID)); // [4][N]
    float* er1 = el1 + (size_t)NH * NN;                   // [4][N]
    u8*    f2q = (u8*)(er1 + (size_t)NH * NN);            // N*64 fp8
    float* el2 = (float*)(f2q + (size_t)NN * HID);        // N
    float* er2 = el2 + NN;                                // N
    float* h2  = er2 + NN;                                // N*64 fp32

    k1_mfma<<<K1_GRID, 256, 0, stream>>>(feat_ids, emb, W1, a_l1, a_r1, f1q, el1, er1);
    k2_attn_agg1<<<dim3(NN / 16, NH), 256, 0, stream>>>(src, f1q, el1, er1, b1, h1q);
    k3_mfma<<<K3_GRID, 256, 0, stream>>>(h1q, W2, a_l2, a_r2, f2q, el2, er2);
    k4_attn_agg2<<<NN / 16, 256, 0, stream>>>(src, f2q, el2, er2, b2, h2);
    k5_score_loss<<<1, 256, 0, stream>>>(h2, user_ids, item_ids, out_scores, out_labels, out_loss);
}